// Round 6
// baseline (90.471 us; speedup 1.0000x reference)
//
#include <hip/hip_runtime.h>
#include <hip/hip_bf16.h>

// Problem: B=8192, D=256, INNER=64, OUT=256, fp32 in/out.
//   inner[b,d] = b2[d] + sum_i relu(x[b,d]*w1[d,i]+b1[d,i])*w2[d,i]
//   g[b,j]     = relu(sum_d inner[b,d]*wo1[j,d] + bo1[j])
//   out[b,o]   = sum_j g[b,j]*wo2[o,j] + bo2[o]
//
// R6: step A was L2-BW co-limited (4096 waves x 64 KB pa = 268 MB ~ 34 TB/s
// ~ L2 ceiling). pa now bf16x4 (w1,b1,w2,pad in 8 B) -> 134 MB; 3 shift-
// converts per i (+12% VALU, net win). Steps B/C unchanged: bf16 MFMA
// 16x16x32, fp32 accum.

#define B_TOT 8192
#define D_DIM 256
#define I_DIM 64
#define O_DIM 256
#define RB 16          // batch rows per block
#define NT 512         // threads per block

typedef __hip_bfloat16 bf16;
using short8 = __attribute__((ext_vector_type(8))) short;
using f32x4  = __attribute__((ext_vector_type(4))) float;

// d_ws layout:
//   pa  : ushort4[64*256] @ byte 0       (128 KB)  (w1[d][i],b1[d][i],w2[d][i],0) bf16 at [i*256+d]
//   pbB : bf16[8*64*32]   @ byte 131072  (32 KB)   pbB[(kc*64+j)*32+kk]  = wo1[j][kc*32+kk]
//   pcB : bf16[2*256*32]  @ byte 163840  (32 KB)   pcB[(kc*256+o)*32+kk] = wo2[o][kc*32+kk]

static __device__ __forceinline__ unsigned short f2bf(float v) {
    bf16 h = __float2bfloat16(v);
    return *(unsigned short*)&h;
}

__global__ __launch_bounds__(256)
void kal_prep(const float* __restrict__ w1, const float* __restrict__ b1,
              const float* __restrict__ w2, const float* __restrict__ wo1,
              const float* __restrict__ wo2, void* __restrict__ ws) {
    int idx = blockIdx.x * 256 + threadIdx.x;   // 0 .. 49151
    if (idx < 16384) {
        int i = idx >> 8;          // 0..63
        int d = idx & 255;         // 0..255
        ushort4 v;
        v.x = f2bf(w1[d * I_DIM + i]);
        v.y = f2bf(b1[d * I_DIM + i]);
        v.z = f2bf(w2[d * I_DIM + i]);
        v.w = 0;
        ((ushort4*)ws)[idx] = v;
    } else if (idx < 32768) {
        int r   = idx - 16384;     // 0..16383 : pbB
        int kc  = r >> 11;         // 0..7
        int rem = r & 2047;
        int j   = rem >> 5;        // 0..63
        int kk  = rem & 31;        // 0..31
        unsigned short* pbB = (unsigned short*)((char*)ws + 131072);
        pbB[r] = f2bf(wo1[j * D_DIM + kc * 32 + kk]);
    } else if (idx < 49152) {
        int r   = idx - 32768;     // 0..16383 : pcB
        int kc  = r >> 13;         // 0..1
        int rem = r & 8191;
        int o   = rem >> 5;        // 0..255
        int kk  = rem & 31;        // 0..31
        unsigned short* pcB = (unsigned short*)((char*)ws + 163840);
        pcB[r] = f2bf(wo2[o * I_DIM + kc * 32 + kk]);
    }
}

__global__ __launch_bounds__(NT)
void kal_main(const float* __restrict__ x,  const float* __restrict__ b2,
              const float* __restrict__ bo1, const float* __restrict__ bo2,
              const void* __restrict__ ws, float* __restrict__ out) {
    const ushort4* pa  = (const ushort4*)ws;
    const bf16*    pbB = (const bf16*)((const char*)ws + 131072);
    const bf16*    pcB = (const bf16*)((const char*)ws + 163840);

    __shared__ bf16 inner_bf[RB][264];   // +8 pad: b128 frag reads <=2-way bank alias
    __shared__ bf16 g_bf[RB][72];        // +8 pad

    const int t    = threadIdx.x;
    const int row0 = blockIdx.x * RB;

    // ---------------- Step A: per-feature inner MLPs (fp32 VALU) ------------
    {
        const int d    = t & 255;
        const int half = t >> 8;          // waves 0-3: rows 0-7, waves 4-7: rows 8-15
        float xv[8], acc[8];
        const float b2v = b2[d];
        #pragma unroll
        for (int b = 0; b < 8; ++b) {
            xv[b]  = x[(row0 + half * 8 + b) * D_DIM + d];   // coalesced
            acc[b] = b2v;
        }
        #pragma unroll 8
        for (int i = 0; i < I_DIM; ++i) {
            const ushort4 wq = pa[i * D_DIM + d];   // one dwordx2: bf16 (w1,b1,w2,_)
            const float w1v = __uint_as_float((unsigned)wq.x << 16);
            const float b1v = __uint_as_float((unsigned)wq.y << 16);
            const float w2v = __uint_as_float((unsigned)wq.z << 16);
            #pragma unroll
            for (int b = 0; b < 8; ++b) {
                float h = fmaf(xv[b], w1v, b1v);
                h = fmaxf(h, 0.0f);
                acc[b] = fmaf(h, w2v, acc[b]);
            }
        }
        #pragma unroll
        for (int b = 0; b < 8; ++b)
            inner_bf[half * 8 + b][d] = __float2bfloat16(acc[b]);
    }
    __syncthreads();

    const int lane = t & 63;
    const int wave = t >> 6;
    const int col  = lane & 15;    // MFMA m/n index
    const int quad = lane >> 4;    // MFMA k-group / row-group

    // ---------------- Step B: [16x256] @ wo1^T -> [16x64], MFMA -------------
    if (wave < 4) {
        const int j0 = wave * 16;            // N-tile
        f32x4 acc = {0.f, 0.f, 0.f, 0.f};
        #pragma unroll
        for (int kc = 0; kc < 8; ++kc) {
            // A-frag: inner[m=col][k=kc*32+quad*8 ..+7], 16B LDS read
            short8 af = *(const short8*)&inner_bf[col][kc * 32 + quad * 8];
            // B-frag: wo1 pre-packed, coalesced dwordx4
            short8 bfr = *(const short8*)&pbB[(kc * 64 + j0 + col) * 32 + quad * 8];
            acc = __builtin_amdgcn_mfma_f32_16x16x32_bf16(af, bfr, acc, 0, 0, 0);
        }
        const float bo1v = bo1[j0 + col];
        #pragma unroll
        for (int r = 0; r < 4; ++r) {
            const int row = quad * 4 + r;    // C/D: row = quad*4+reg, col = lane&15
            g_bf[row][j0 + col] = __float2bfloat16(fmaxf(acc[r] + bo1v, 0.0f));
        }
    }
    __syncthreads();

    // ---------------- Step C: [16x64] @ wo2^T -> [16x256], MFMA -------------
    #pragma unroll
    for (int tile = 0; tile < 2; ++tile) {
        const int o0 = wave * 16 + tile * 128;   // 8 waves x 2 tiles = 16 N-tiles
        f32x4 acc = {0.f, 0.f, 0.f, 0.f};
        #pragma unroll
        for (int kc = 0; kc < 2; ++kc) {
            short8 af = *(const short8*)&g_bf[col][kc * 32 + quad * 8];
            short8 bfr = *(const short8*)&pcB[(kc * 256 + o0 + col) * 32 + quad * 8];
            acc = __builtin_amdgcn_mfma_f32_16x16x32_bf16(af, bfr, acc, 0, 0, 0);
        }
        const float bo2v = bo2[o0 + col];
        #pragma unroll
        for (int r = 0; r < 4; ++r)
            out[(row0 + quad * 4 + r) * O_DIM + o0 + col] = acc[r] + bo2v;
    }
}

extern "C" void kernel_launch(void* const* d_in, const int* in_sizes, int n_in,
                              void* d_out, int out_size, void* d_ws, size_t ws_size,
                              hipStream_t stream) {
    const float* x   = (const float*)d_in[0];
    const float* w1  = (const float*)d_in[1];
    const float* b1  = (const float*)d_in[2];
    const float* w2  = (const float*)d_in[3];
    const float* b2  = (const float*)d_in[4];
    const float* wo1 = (const float*)d_in[5];
    const float* bo1 = (const float*)d_in[6];
    const float* wo2 = (const float*)d_in[7];
    const float* bo2 = (const float*)d_in[8];
    float* out = (float*)d_out;

    kal_prep<<<(49152 + 255) / 256, 256, 0, stream>>>(w1, b1, w2, wo1, wo2, d_ws);
    kal_main<<<B_TOT / RB, NT, 0, stream>>>(x, b2, bo1, bo2, d_ws, out);
}